// Round 2
// baseline (485.188 us; speedup 1.0000x reference)
//
#include <hip/hip_runtime.h>

// Problem constants: B=16, P=1024, E=1024, H=16, DH=64
#define PB 16
#define PP 1024
#define PE 1024
#define PH 16
#define PDH 64

typedef __attribute__((ext_vector_type(8))) short bf16x8;
typedef __attribute__((ext_vector_type(4))) short bf16x4;
typedef __attribute__((ext_vector_type(4))) float f32x4;

#define LOG2E 1.44269504088896340736f

__device__ __forceinline__ short f2bf(float f) {
    union { float f; unsigned u; } a;
    a.f = f;
    unsigned u = a.u;
    u += 0x7fffu + ((u >> 16) & 1u);   // round-to-nearest-even
    return (short)(u >> 16);
}
__device__ __forceinline__ float bf2f(short s) {
    union { unsigned u; float f; } a;
    a.u = ((unsigned)(unsigned short)s) << 16;
    return a.f;
}
// pack two f32 -> one dword of 2 bf16 (src0 in low half)
__device__ __forceinline__ unsigned cvtpk(float lo, float hi) {
    unsigned r;
    asm("v_cvt_pk_bf16_f32 %0, %1, %2" : "=v"(r) : "v"(lo), "v"(hi));
    return r;
}
union U8 { unsigned u[4]; bf16x8 v; };
// async global->LDS, 16B per lane; LDS dest = wave-uniform base + lane*16
__device__ __forceinline__ void async16(const void* g, void* l) {
    __builtin_amdgcn_global_load_lds(
        (const __attribute__((address_space(1))) unsigned int*)g,
        (__attribute__((address_space(3))) unsigned int*)l, 16, 0, 0);
}

// ---------------------------------------------------------------------------
// Kernel 0a: biasb[h][q][kv] = bf16(bias[h][q][kv] * log2e)  (pure convert)
// ---------------------------------------------------------------------------
__global__ __launch_bounds__(256) void bias_conv(const float* __restrict__ bias,
                                                 short* __restrict__ biasb) {
    size_t idx = ((size_t)blockIdx.x * 256 + threadIdx.x) * 8;
    float4 a = *(const float4*)(bias + idx);
    float4 b = *(const float4*)(bias + idx + 4);
    bf16x8 t = {f2bf(a.x * LOG2E), f2bf(a.y * LOG2E), f2bf(a.z * LOG2E), f2bf(a.w * LOG2E),
                f2bf(b.x * LOG2E), f2bf(b.y * LOG2E), f2bf(b.z * LOG2E), f2bf(b.w * LOG2E)};
    *(bf16x8*)(biasb + idx) = t;
}

// ---------------------------------------------------------------------------
// Kernel 0b: weight fp32 -> bf16 (wv_w and out_w, both [n][k] row-major)
// ---------------------------------------------------------------------------
__global__ __launch_bounds__(256) void wconv(const float* __restrict__ wvw,
                                             const float* __restrict__ outw,
                                             short* __restrict__ wvwb,
                                             short* __restrict__ outwb) {
    int bid = blockIdx.x;
    const float* src = (bid < 512) ? wvw : outw;
    short* dst = (bid < 512) ? wvwb : outwb;
    int lb = (bid < 512) ? bid : bid - 512;
    size_t idx = ((size_t)lb * 256 + threadIdx.x) * 8;
    float4 a = *(const float4*)(src + idx);
    float4 b = *(const float4*)(src + idx + 4);
    bf16x8 t = {f2bf(a.x), f2bf(a.y), f2bf(a.z), f2bf(a.w),
                f2bf(b.x), f2bf(b.y), f2bf(b.z), f2bf(b.w)};
    *(bf16x8*)(dst + idx) = t;
}

// ---------------------------------------------------------------------------
// Kernel 1: xw = (x_h @ w_att_val[h]) * 0.125 * log2e (bf16)  AND  xbf = bf16(x)
// ---------------------------------------------------------------------------
__global__ __launch_bounds__(256) void xw_kernel(const float* __restrict__ x,
                                                 const float* __restrict__ watt,
                                                 short* __restrict__ xw,
                                                 short* __restrict__ xbf) {
    int bid = blockIdx.x;
    int q4 = bid & 3;
    int bh = bid >> 2;          // b*16 + h
    int h = bh & 15;
    __shared__ short Wt[64][88];   // W^T: Wt[e'][d]

    int tid = threadIdx.x;
    {
        const float* W = watt + (size_t)h * 4096;
        int idx = tid * 16;
        int d = idx >> 6, e0 = idx & 63;
#pragma unroll
        for (int i = 0; i < 16; i += 4) {
            float4 v = *(const float4*)(W + d * 64 + e0 + i);
            Wt[e0 + i + 0][d] = f2bf(v.x);
            Wt[e0 + i + 1][d] = f2bf(v.y);
            Wt[e0 + i + 2][d] = f2bf(v.z);
            Wt[e0 + i + 3][d] = f2bf(v.w);
        }
    }
    __syncthreads();

    int wave = tid >> 6, lane = tid & 63;
    int lm = lane & 15, lq = lane >> 4;

    bf16x8 bfr[4][2];
#pragma unroll
    for (int nt = 0; nt < 4; nt++)
#pragma unroll
        for (int kf = 0; kf < 2; kf++)
            bfr[nt][kf] = *(const bf16x8*)&Wt[nt * 16 + lm][kf * 32 + lq * 8];

    int b = bh >> 4;
    const float QSCALE = 0.125f * LOG2E;
    for (int pass = 0; pass < 4; pass++) {
        int p0 = q4 * 256 + pass * 64 + wave * 16;
        const float* xrow = x + ((size_t)(b * 1024 + p0 + lm)) * 1024 + h * 64;
        short* xorow = xbf + ((size_t)(b * 1024 + p0 + lm)) * 1024 + h * 64;
        bf16x8 af[2];
#pragma unroll
        for (int kf = 0; kf < 2; kf++) {
            float4 v0 = *(const float4*)(xrow + kf * 32 + lq * 8);
            float4 v1 = *(const float4*)(xrow + kf * 32 + lq * 8 + 4);
            bf16x8 t;
            t[0] = f2bf(v0.x); t[1] = f2bf(v0.y); t[2] = f2bf(v0.z); t[3] = f2bf(v0.w);
            t[4] = f2bf(v1.x); t[5] = f2bf(v1.y); t[6] = f2bf(v1.z); t[7] = f2bf(v1.w);
            af[kf] = t;
            *(bf16x8*)(xorow + kf * 32 + lq * 8) = t;   // bf16 copy of x
        }
#pragma unroll
        for (int nt = 0; nt < 4; nt++) {
            f32x4 acc = {0.f, 0.f, 0.f, 0.f};
            acc = __builtin_amdgcn_mfma_f32_16x16x32_bf16(af[0], bfr[nt][0], acc, 0, 0, 0);
            acc = __builtin_amdgcn_mfma_f32_16x16x32_bf16(af[1], bfr[nt][1], acc, 0, 0, 0);
            size_t base = ((size_t)bh * 1024 + p0 + lq * 4) * 64 + nt * 16 + lm;
#pragma unroll
            for (int r = 0; r < 4; r++)
                xw[base + (size_t)r * 64] = f2bf(acc[r] * QSCALE);
        }
    }
}

// ---------------------------------------------------------------------------
// Kernel 2: vt[b,h,d,p] = (x @ wv_w^T + wv_b) transposed (bf16).
// ---------------------------------------------------------------------------
__global__ __launch_bounds__(256) void vx_gemm(const short* __restrict__ xbf,
                                               const short* __restrict__ wvwb,
                                               const float* __restrict__ wvb,
                                               short* __restrict__ vt) {
    int mblk = blockIdx.x >> 3, nblk = blockIdx.x & 7;
    int m0 = mblk * 128, n0 = nblk * 128;
    __shared__ short As[128 * 32];
    __shared__ short Bs[128 * 32];

    int tid = threadIdx.x;
    int wv = tid >> 6, ln = tid & 63;
    int c0 = wv * 2;
    int rrow = ln >> 2, rseg = (ln & 3) * 8;
    const short* gA = xbf + (size_t)(m0 + c0 * 16 + rrow) * 1024 + rseg;
    const short* gB = wvwb + (size_t)(n0 + c0 * 16 + rrow) * 1024 + rseg;
    short* lA = As + c0 * 512;
    short* lB = Bs + c0 * 512;

    int lane = ln, lm = lane & 15, lq = lane >> 4;
    int wm = (wv >> 1) * 64, wn = (wv & 1) * 64;

    f32x4 acc[4][4];
#pragma unroll
    for (int i = 0; i < 4; i++)
#pragma unroll
        for (int j = 0; j < 4; j++) acc[i][j] = (f32x4){0.f, 0.f, 0.f, 0.f};

    for (int k0 = 0; k0 < 1024; k0 += 32) {
        __syncthreads();
        async16(gA + k0, lA);
        async16(gA + k0 + 16 * 1024, lA + 512);
        async16(gB + k0, lB);
        async16(gB + k0 + 16 * 1024, lB + 512);
        __syncthreads();
        bf16x8 af[4], bfr[4];
#pragma unroll
        for (int mt = 0; mt < 4; mt++) af[mt] = *(const bf16x8*)&As[(wm + mt * 16 + lm) * 32 + lq * 8];
#pragma unroll
        for (int nt = 0; nt < 4; nt++) bfr[nt] = *(const bf16x8*)&Bs[(wn + nt * 16 + lm) * 32 + lq * 8];
#pragma unroll
        for (int mt = 0; mt < 4; mt++)
#pragma unroll
            for (int nt = 0; nt < 4; nt++)
                acc[mt][nt] = __builtin_amdgcn_mfma_f32_16x16x32_bf16(af[mt], bfr[nt], acc[mt][nt], 0, 0, 0);
    }

#pragma unroll
    for (int nt = 0; nt < 4; nt++) {
        int e = n0 + wn + nt * 16 + lm;
        float bias = wvb[e];
        int hh = e >> 6, dd = e & 63;
#pragma unroll
        for (int mt = 0; mt < 4; mt++) {
            int pg = m0 + wm + mt * 16 + lq * 4;
            int bb = pg >> 10, pp = pg & 1023;
            bf16x4 pk;
#pragma unroll
            for (int r = 0; r < 4; r++) pk[r] = f2bf(acc[mt][nt][r] + bias);
            *(bf16x4*)(vt + ((size_t)((bb * 16 + hh) * 64 + dd)) * 1024 + pp) = pk;
        }
    }
}

// ---------------------------------------------------------------------------
// Kernel 3: flash attention v5 — swapped QK^T (P stays in registers) +
// double-buffered K/V staged via global_load_lds (width 16) with XOR-swizzled
// global source (LDS stays linear [64][64]; reads apply slot^=(row&7)).
// One barrier per tile. launch_bounds(256,4) for 4 waves/SIMD.
// ---------------------------------------------------------------------------
__global__ __launch_bounds__(256, 4) void flash_kernel(const short* __restrict__ xbf,
                                                       const short* __restrict__ xw,
                                                       const short* __restrict__ vt,
                                                       const short* __restrict__ biasb,
                                                       short* __restrict__ obuf) {
    int bid = blockIdx.x;
    int qblk = bid & 7, b = (bid >> 3) & 15, h = bid >> 7;
    int bh = b * 16 + h;
    int q0 = qblk * 128;

    __shared__ short Kb[2][64 * 64];   // K[kv][d]   (16B slots XOR-swizzled by row&7)
    __shared__ short Vb[2][64 * 64];   // V^T[d][kv] (same swizzle)
    __shared__ float Rs[4][36];        // per-wave row-sum redistribution

    int tid = threadIdx.x, wave = tid >> 6, lane = tid & 63;
    int lm = lane & 15, lq = lane >> 4;

    // Q fragments: B-operand of the swapped QK^T (lane lm = q column).
    bf16x8 qa[2][2];
#pragma unroll
    for (int qt = 0; qt < 2; qt++)
#pragma unroll
        for (int kf = 0; kf < 2; kf++)
            qa[qt][kf] = *(const bf16x8*)(xw + ((size_t)bh * 1024 + q0 + wave * 32 + qt * 16 + lm) * 64 + kf * 32 + lq * 8);

    f32x4 o[2][4];
#pragma unroll
    for (int qt = 0; qt < 2; qt++)
#pragma unroll
        for (int dt = 0; dt < 4; dt++) o[qt][dt] = (f32x4){0.f, 0.f, 0.f, 0.f};
    float rs[2] = {0.f, 0.f};

    // --- async staging geometry -------------------------------------------
    // Wave w, call j in {0,1} fills LDS bytes [w*2048 + j*1024, +1024):
    //   lane l -> phys row r = w*16 + j*8 + (l>>3), phys 16B slot (l&7).
    // Linear LDS; the SOURCE is pre-swizzled so phys slot c holds logical
    // slot c ^ (r&7). Readers apply the same XOR -> conflict-optimal.
    int srow = lane >> 3;                  // 0..7  (== r&7)
    int sslot = (lane & 7) ^ srow;         // swizzled logical 16B slot
    const short* kg = xbf + ((size_t)(b * 1024)) * 1024 + h * 64;
    const short* vg = vt + ((size_t)bh * 64) * 1024;
    const short* kp = kg + (size_t)(wave * 16 + srow) * 1024 + sslot * 8;  // + kv*1024 per tile
    const short* vp = vg + (size_t)(wave * 16 + srow) * 1024 + sslot * 8;  // + kv     per tile
    // bias in [h][q][kv] layout (pre-scaled by log2e)
    const short* bg = biasb + ((size_t)h << 20) + (size_t)(q0 + wave * 32) * 1024;

    bf16x4 br[4][2];
    // prologue: issue tile-0 staging + bias prefetch
    {
        short* Kd = Kb[0] + wave * 1024;
        short* Vd = Vb[0] + wave * 1024;
        async16(kp, Kd);
        async16(kp + 8 * 1024, Kd + 512);
        async16(vp, Vd);
        async16(vp + 8 * 1024, Vd + 512);
#pragma unroll
        for (int kt = 0; kt < 4; kt++)
#pragma unroll
            for (int qt = 0; qt < 2; qt++)
                br[kt][qt] = *(const bf16x4*)(bg + (size_t)(qt * 16 + lm) * 1024 + kt * 16 + lq * 4);
    }

    for (int tile = 0; tile < 16; tile++) {
        const int cur = tile & 1;
        __syncthreads();   // drains vmcnt: tile's K/V in LDS, bias regs ready

        // issue next tile's staging into the other buffer (readers of it
        // finished before the barrier above)
        if (tile < 15) {
            int kvn = (tile + 1) * 64;
            short* Kd = Kb[cur ^ 1] + wave * 1024;
            short* Vd = Vb[cur ^ 1] + wave * 1024;
            const short* kpn = kp + (size_t)kvn * 1024;
            const short* vpn = vp + kvn;
            async16(kpn, Kd);
            async16(kpn + 8 * 1024, Kd + 512);
            async16(vpn, Vd);
            async16(vpn + 8 * 1024, Vd + 512);
        }

        // acc init from prefetched bias regs:
        // s[kt][qt] elem r -> (kv = kv0+kt*16+lq*4+r, q = q0+wave*32+qt*16+lm)
        f32x4 s[4][2];
#pragma unroll
        for (int kt = 0; kt < 4; kt++)
#pragma unroll
            for (int qt = 0; qt < 2; qt++) {
                bf16x4 bv = br[kt][qt];
                s[kt][qt] = (f32x4){bf2f(bv[0]), bf2f(bv[1]), bf2f(bv[2]), bf2f(bv[3])};
            }

        // prefetch next tile's bias into regs — overlaps compute
        if (tile < 15) {
            int kvn = (tile + 1) * 64;
#pragma unroll
            for (int kt = 0; kt < 4; kt++)
#pragma unroll
                for (int qt = 0; qt < 2; qt++)
                    br[kt][qt] = *(const bf16x4*)(bg + (size_t)(qt * 16 + lm) * 1024 + kvn + kt * 16 + lq * 4);
        }

        const short* Kc = Kb[cur];
        const short* Vc = Vb[cur];

        // S^T = K Q^T + bias  (A = K rows=kv, B = Q cols=q)
        __builtin_amdgcn_s_setprio(1);
#pragma unroll
        for (int kf = 0; kf < 2; kf++) {
            bf16x8 ka[4];
#pragma unroll
            for (int kt = 0; kt < 4; kt++) {
                int R = kt * 16 + lm;
                ka[kt] = *(const bf16x8*)&Kc[R * 64 + (((kf * 4 + lq) ^ (lm & 7)) << 3)];
            }
#pragma unroll
            for (int kt = 0; kt < 4; kt++)
#pragma unroll
                for (int qt = 0; qt < 2; qt++)
                    s[kt][qt] = __builtin_amdgcn_mfma_f32_16x16x32_bf16(ka[kt], qa[qt][kf], s[kt][qt], 0, 0, 0);
        }
        __builtin_amdgcn_s_setprio(0);

        // fixed-max softmax in place: p = exp2(s); accumulate partial row sums
#pragma unroll
        for (int kt = 0; kt < 4; kt++)
#pragma unroll
            for (int qt = 0; qt < 2; qt++)
#pragma unroll
                for (int r = 0; r < 4; r++) {
                    float pv = __builtin_amdgcn_exp2f(s[kt][qt][r]);
                    s[kt][qt][r] = pv;
                    rs[qt] += pv;
                }

        // O += P V.  P stays in registers; per-lane k-order for k-group lq is
        // {kf*32 + lq*4 + 0..3, kf*32 + 16 + lq*4 + 0..3}; V frag matches.
        __builtin_amdgcn_s_setprio(1);
#pragma unroll
        for (int kf = 0; kf < 2; kf++) {
            bf16x8 pa[2];
#pragma unroll
            for (int qt = 0; qt < 2; qt++) {
                U8 u;
                u.u[0] = cvtpk(s[kf * 2][qt][0], s[kf * 2][qt][1]);
                u.u[1] = cvtpk(s[kf * 2][qt][2], s[kf * 2][qt][3]);
                u.u[2] = cvtpk(s[kf * 2 + 1][qt][0], s[kf * 2 + 1][qt][1]);
                u.u[3] = cvtpk(s[kf * 2 + 1][qt][2], s[kf * 2 + 1][qt][3]);
                pa[qt] = u.v;
            }
#pragma unroll
            for (int dt = 0; dt < 4; dt++) {
                int R = dt * 16 + lm;
                U8 uv;
                // logical cols (shorts): kf*32 + lq*4 (half0), +16 (half1)
                *(bf16x4*)&uv.u[0] = *(const bf16x4*)&Vc[R * 64 +
                    ((((kf * 4 + (lq >> 1)) ^ (lm & 7)) << 3) + ((lq & 1) << 2))];
                *(bf16x4*)&uv.u[2] = *(const bf16x4*)&Vc[R * 64 +
                    ((((kf * 4 + 2 + (lq >> 1)) ^ (lm & 7)) << 3) + ((lq & 1) << 2))];
#pragma unroll
                for (int qt = 0; qt < 2; qt++)
                    o[qt][dt] = __builtin_amdgcn_mfma_f32_16x16x32_bf16(pa[qt], uv.v, o[qt][dt], 0, 0, 0);
            }
        }
        __builtin_amdgcn_s_setprio(0);
    }

    // row sums: butterfly across lq (lanes ^16, ^32), park in LDS, re-read at
    // the o-layout q index (lq*4+r).
#pragma unroll
    for (int qt = 0; qt < 2; qt++) {
        rs[qt] += __shfl_xor(rs[qt], 16);
        rs[qt] += __shfl_xor(rs[qt], 32);
    }
    if (lq == 0) { Rs[wave][lm] = rs[0]; Rs[wave][16 + lm] = rs[1]; }
    __syncthreads();

#pragma unroll
    for (int qt = 0; qt < 2; qt++) {
        float inv[4];
#pragma unroll
        for (int r = 0; r < 4; r++)
            inv[r] = 1.f / Rs[wave][qt * 16 + lq * 4 + r];
#pragma unroll
        for (int dt = 0; dt < 4; dt++) {
            int e = h * 64 + dt * 16 + lm;
#pragma unroll
            for (int r = 0; r < 4; r++) {
                int p = q0 + wave * 32 + qt * 16 + lq * 4 + r;
                obuf[((size_t)(b * 1024 + p)) * 1024 + e] = f2bf(o[qt][dt][r] * inv[r]);
            }
        }
    }
}

// ---------------------------------------------------------------------------
// Kernel 4: out = obuf @ out_w^T + out_b (fp32). m97-style staging.
// ---------------------------------------------------------------------------
__global__ __launch_bounds__(256) void out_gemm(const short* __restrict__ obuf,
                                                const short* __restrict__ outwb,
                                                const float* __restrict__ outb,
                                                float* __restrict__ out) {
    int mblk = blockIdx.x >> 3, nblk = blockIdx.x & 7;
    int m0 = mblk * 128, n0 = nblk * 128;
    __shared__ short As[128 * 32];
    __shared__ short Bs[128 * 32];

    int tid = threadIdx.x;
    int wv = tid >> 6, ln = tid & 63;
    int c0 = wv * 2;
    int rrow = ln >> 2, rseg = (ln & 3) * 8;
    const short* gA = obuf + (size_t)(m0 + c0 * 16 + rrow) * 1024 + rseg;
    const short* gB = outwb + (size_t)(n0 + c0 * 16 + rrow) * 1024 + rseg;
    short* lA = As + c0 * 512;
    short* lB = Bs + c0 * 512;

    int lm = ln & 15, lq = ln >> 4;
    int wm = (wv >> 1) * 64, wn = (wv & 1) * 64;

    f32x4 acc[4][4];
#pragma unroll
    for (int i = 0; i < 4; i++)
#pragma unroll
        for (int j = 0; j < 4; j++) acc[i][j] = (f32x4){0.f, 0.f, 0.f, 0.f};

    for (int k0 = 0; k0 < 1024; k0 += 32) {
        __syncthreads();
        async16(gA + k0, lA);
        async16(gA + k0 + 16 * 1024, lA + 512);
        async16(gB + k0, lB);
        async16(gB + k0 + 16 * 1024, lB + 512);
        __syncthreads();
        bf16x8 af[4], bfr[4];
#pragma unroll
        for (int mt = 0; mt < 4; mt++) af[mt] = *(const bf16x8*)&As[(wm + mt * 16 + lm) * 32 + lq * 8];
#pragma unroll
        for (int nt = 0; nt < 4; nt++) bfr[nt] = *(const bf16x8*)&Bs[(wn + nt * 16 + lm) * 32 + lq * 8];
#pragma unroll
        for (int mt = 0; mt < 4; mt++)
#pragma unroll
            for (int nt = 0; nt < 4; nt++)
                acc[mt][nt] = __builtin_amdgcn_mfma_f32_16x16x32_bf16(af[mt], bfr[nt], acc[mt][nt], 0, 0, 0);
    }

#pragma unroll
    for (int nt = 0; nt < 4; nt++) {
        int e = n0 + wn + nt * 16 + lm;
        float bias = outb[e];
#pragma unroll
        for (int mt = 0; mt < 4; mt++) {
            int pg = m0 + wm + mt * 16 + lq * 4;
#pragma unroll
            for (int r = 0; r < 4; r++)
                out[(size_t)(pg + r) * 1024 + e] = acc[mt][nt][r] + bias;
        }
    }
}

extern "C" void kernel_launch(void* const* d_in, const int* in_sizes, int n_in,
                              void* d_out, int out_size, void* d_ws, size_t ws_size,
                              hipStream_t stream) {
    const float* x    = (const float*)d_in[0];  // [16,1024,1024]
    const float* watt = (const float*)d_in[1];  // [16,64,64]
    const float* bias = (const float*)d_in[2];  // [16,1024,1024]
    const float* wvw  = (const float*)d_in[3];  // [1024,1024]
    const float* wvb  = (const float*)d_in[4];  // [1024]
    const float* outw = (const float*)d_in[5];  // [1024,1024]
    const float* outb = (const float*)d_in[6];  // [1024]
    float* out = (float*)d_out;

    char* ws = (char*)d_ws;
    short* xw     = (short*)ws;                           // 32 MB  [B,H,P,DH] bf16 (Q, pre-scaled 0.125*log2e)
    short* vt     = (short*)(ws + ((size_t)32 << 20));    // 32 MB  [B,H,DH,P] bf16 (V^T)
    short* obuf   = (short*)(ws + ((size_t)64 << 20));    // 32 MB  [B,P,E]    bf16 (attn out)
    short* biasb  = (short*)(ws + ((size_t)96 << 20));    // 32 MB  [H,P,P]    bf16 (bias*log2e, original layout)
    short* xbf    = (short*)(ws + ((size_t)128 << 20));   // 32 MB  [B,P,E]    bf16 (x)
    short* wvwb   = (short*)(ws + ((size_t)160 << 20));   // 2 MB
    short* outwb  = (short*)(ws + ((size_t)162 << 20));   // 2 MB

    xw_kernel<<<PB * PH * 4, 256, 0, stream>>>(x, watt, xw, xbf);
    bias_conv<<<8192, 256, 0, stream>>>(bias, biasb);
    wconv<<<1024, 256, 0, stream>>>(wvw, outw, wvwb, outwb);
    vx_gemm<<<(PB * PP / 128) * (PE / 128), 256, 0, stream>>>(xbf, wvwb, wvb, vt);
    flash_kernel<<<PB * PH * (PP / 128), 256, 0, stream>>>(xbf, xw, vt, biasb, obuf);
    out_gemm<<<(PB * PP / 128) * (PE / 128), 256, 0, stream>>>(obuf, outwb, outb, out);
}

// Round 3
// 423.174 us; speedup vs baseline: 1.1465x; 1.1465x over previous
//
#include <hip/hip_runtime.h>

// Problem constants: B=16, P=1024, E=1024, H=16, DH=64
#define PB 16
#define PP 1024
#define PE 1024
#define PH 16
#define PDH 64

typedef __attribute__((ext_vector_type(8))) short bf16x8;
typedef __attribute__((ext_vector_type(4))) short bf16x4;
typedef __attribute__((ext_vector_type(4))) float f32x4;

#define LOG2E 1.44269504088896340736f

__device__ __forceinline__ short f2bf(float f) {
    union { float f; unsigned u; } a;
    a.f = f;
    unsigned u = a.u;
    u += 0x7fffu + ((u >> 16) & 1u);   // round-to-nearest-even
    return (short)(u >> 16);
}
__device__ __forceinline__ float bf2f(short s) {
    union { unsigned u; float f; } a;
    a.u = ((unsigned)(unsigned short)s) << 16;
    return a.f;
}
// pack two f32 -> one dword of 2 bf16 (src0 in low half)
__device__ __forceinline__ unsigned cvtpk(float lo, float hi) {
    unsigned r;
    asm("v_cvt_pk_bf16_f32 %0, %1, %2" : "=v"(r) : "v"(lo), "v"(hi));
    return r;
}
union U8 { unsigned u[4]; bf16x8 v; };
// async global->LDS, 16B per lane; LDS dest = wave-uniform base + lane*16
__device__ __forceinline__ void async16(const void* g, void* l) {
    __builtin_amdgcn_global_load_lds(
        (const __attribute__((address_space(1))) unsigned int*)g,
        (__attribute__((address_space(3))) unsigned int*)l, 16, 0, 0);
}

// ---------------------------------------------------------------------------
// Kernel 0b: weight fp32 -> bf16 (wv_w and out_w, both [n][k] row-major)
// ---------------------------------------------------------------------------
__global__ __launch_bounds__(256) void wconv(const float* __restrict__ wvw,
                                             const float* __restrict__ outw,
                                             short* __restrict__ wvwb,
                                             short* __restrict__ outwb) {
    int bid = blockIdx.x;
    const float* src = (bid < 512) ? wvw : outw;
    short* dst = (bid < 512) ? wvwb : outwb;
    int lb = (bid < 512) ? bid : bid - 512;
    size_t idx = ((size_t)lb * 256 + threadIdx.x) * 8;
    float4 a = *(const float4*)(src + idx);
    float4 b = *(const float4*)(src + idx + 4);
    bf16x8 t = {f2bf(a.x), f2bf(a.y), f2bf(a.z), f2bf(a.w),
                f2bf(b.x), f2bf(b.y), f2bf(b.z), f2bf(b.w)};
    *(bf16x8*)(dst + idx) = t;
}

// ---------------------------------------------------------------------------
// Kernel 1: xw = (x_h @ w_att_val[h]) * 0.125 * log2e (bf16)  AND  xbf = bf16(x)
// ---------------------------------------------------------------------------
__global__ __launch_bounds__(256) void xw_kernel(const float* __restrict__ x,
                                                 const float* __restrict__ watt,
                                                 short* __restrict__ xw,
                                                 short* __restrict__ xbf) {
    int bid = blockIdx.x;
    int q4 = bid & 3;
    int bh = bid >> 2;          // b*16 + h
    int h = bh & 15;
    __shared__ short Wt[64][88];   // W^T: Wt[e'][d]

    int tid = threadIdx.x;
    {
        const float* W = watt + (size_t)h * 4096;
        int idx = tid * 16;
        int d = idx >> 6, e0 = idx & 63;
#pragma unroll
        for (int i = 0; i < 16; i += 4) {
            float4 v = *(const float4*)(W + d * 64 + e0 + i);
            Wt[e0 + i + 0][d] = f2bf(v.x);
            Wt[e0 + i + 1][d] = f2bf(v.y);
            Wt[e0 + i + 2][d] = f2bf(v.z);
            Wt[e0 + i + 3][d] = f2bf(v.w);
        }
    }
    __syncthreads();

    int wave = tid >> 6, lane = tid & 63;
    int lm = lane & 15, lq = lane >> 4;

    bf16x8 bfr[4][2];
#pragma unroll
    for (int nt = 0; nt < 4; nt++)
#pragma unroll
        for (int kf = 0; kf < 2; kf++)
            bfr[nt][kf] = *(const bf16x8*)&Wt[nt * 16 + lm][kf * 32 + lq * 8];

    int b = bh >> 4;
    const float QSCALE = 0.125f * LOG2E;
    for (int pass = 0; pass < 4; pass++) {
        int p0 = q4 * 256 + pass * 64 + wave * 16;
        const float* xrow = x + ((size_t)(b * 1024 + p0 + lm)) * 1024 + h * 64;
        short* xorow = xbf + ((size_t)(b * 1024 + p0 + lm)) * 1024 + h * 64;
        bf16x8 af[2];
#pragma unroll
        for (int kf = 0; kf < 2; kf++) {
            float4 v0 = *(const float4*)(xrow + kf * 32 + lq * 8);
            float4 v1 = *(const float4*)(xrow + kf * 32 + lq * 8 + 4);
            bf16x8 t;
            t[0] = f2bf(v0.x); t[1] = f2bf(v0.y); t[2] = f2bf(v0.z); t[3] = f2bf(v0.w);
            t[4] = f2bf(v1.x); t[5] = f2bf(v1.y); t[6] = f2bf(v1.z); t[7] = f2bf(v1.w);
            af[kf] = t;
            *(bf16x8*)(xorow + kf * 32 + lq * 8) = t;   // bf16 copy of x
        }
#pragma unroll
        for (int nt = 0; nt < 4; nt++) {
            f32x4 acc = {0.f, 0.f, 0.f, 0.f};
            acc = __builtin_amdgcn_mfma_f32_16x16x32_bf16(af[0], bfr[nt][0], acc, 0, 0, 0);
            acc = __builtin_amdgcn_mfma_f32_16x16x32_bf16(af[1], bfr[nt][1], acc, 0, 0, 0);
            size_t base = ((size_t)bh * 1024 + p0 + lq * 4) * 64 + nt * 16 + lm;
#pragma unroll
            for (int r = 0; r < 4; r++)
                xw[base + (size_t)r * 64] = f2bf(acc[r] * QSCALE);
        }
    }
}

// ---------------------------------------------------------------------------
// Kernel 2: vt[b,h,d,p] = (x @ wv_w^T + wv_b) transposed (bf16).
// XCD-swizzled grid: the 8 nblk-siblings sharing an A panel land on one XCD.
// ---------------------------------------------------------------------------
__global__ __launch_bounds__(256) void vx_gemm(const short* __restrict__ xbf,
                                               const short* __restrict__ wvwb,
                                               const float* __restrict__ wvb,
                                               short* __restrict__ vt) {
    int logical = (blockIdx.x & 7) * 128 + (blockIdx.x >> 3);   // grid 1024 = 8*128
    int mblk = logical >> 3, nblk = logical & 7;
    int m0 = mblk * 128, n0 = nblk * 128;
    __shared__ short As[128 * 32];
    __shared__ short Bs[128 * 32];

    int tid = threadIdx.x;
    int wv = tid >> 6, ln = tid & 63;
    int c0 = wv * 2;
    int rrow = ln >> 2, rseg = (ln & 3) * 8;
    const short* gA = xbf + (size_t)(m0 + c0 * 16 + rrow) * 1024 + rseg;
    const short* gB = wvwb + (size_t)(n0 + c0 * 16 + rrow) * 1024 + rseg;
    short* lA = As + c0 * 512;
    short* lB = Bs + c0 * 512;

    int lane = ln, lm = lane & 15, lq = lane >> 4;
    int wm = (wv >> 1) * 64, wn = (wv & 1) * 64;

    f32x4 acc[4][4];
#pragma unroll
    for (int i = 0; i < 4; i++)
#pragma unroll
        for (int j = 0; j < 4; j++) acc[i][j] = (f32x4){0.f, 0.f, 0.f, 0.f};

    for (int k0 = 0; k0 < 1024; k0 += 32) {
        __syncthreads();
        async16(gA + k0, lA);
        async16(gA + k0 + 16 * 1024, lA + 512);
        async16(gB + k0, lB);
        async16(gB + k0 + 16 * 1024, lB + 512);
        __syncthreads();
        bf16x8 af[4], bfr[4];
#pragma unroll
        for (int mt = 0; mt < 4; mt++) af[mt] = *(const bf16x8*)&As[(wm + mt * 16 + lm) * 32 + lq * 8];
#pragma unroll
        for (int nt = 0; nt < 4; nt++) bfr[nt] = *(const bf16x8*)&Bs[(wn + nt * 16 + lm) * 32 + lq * 8];
#pragma unroll
        for (int mt = 0; mt < 4; mt++)
#pragma unroll
            for (int nt = 0; nt < 4; nt++)
                acc[mt][nt] = __builtin_amdgcn_mfma_f32_16x16x32_bf16(af[mt], bfr[nt], acc[mt][nt], 0, 0, 0);
    }

#pragma unroll
    for (int nt = 0; nt < 4; nt++) {
        int e = n0 + wn + nt * 16 + lm;
        float bias = wvb[e];
        int hh = e >> 6, dd = e & 63;
#pragma unroll
        for (int mt = 0; mt < 4; mt++) {
            int pg = m0 + wm + mt * 16 + lq * 4;
            int bb = pg >> 10, pp = pg & 1023;
            bf16x4 pk;
#pragma unroll
            for (int r = 0; r < 4; r++) pk[r] = f2bf(acc[mt][nt][r] + bias);
            *(bf16x4*)(vt + ((size_t)((bb * 16 + hh) * 64 + dd)) * 1024 + pp) = pk;
        }
    }
}

// ---------------------------------------------------------------------------
// Kernel 3: flash attention v6 — round-1 structure (register-staged K/V,
// two barriers/tile, P in registers via swapped QK^T) + s_setprio around
// MFMA clusters + XCD-swizzled grid + direct fp32 bias (no bias_conv).
// ---------------------------------------------------------------------------
__global__ __launch_bounds__(256, 3) void flash_kernel(const short* __restrict__ xbf,
                                                       const short* __restrict__ xw,
                                                       const short* __restrict__ vt,
                                                       const float* __restrict__ bias,
                                                       short* __restrict__ obuf) {
    // XCD swizzle: grid 2048 = 8*256; hw round-robins XCDs on blockIdx.x%8,
    // so logical qblk/b/h siblings (consecutive logical ids) share an XCD L2.
    int logical = (blockIdx.x & 7) * 256 + (blockIdx.x >> 3);
    int qblk = logical & 7, b = (logical >> 3) & 15, h = logical >> 7;
    int bh = b * 16 + h;
    int q0 = qblk * 128;

    __shared__ short Ks[64][72];       // K[kv][d]
    __shared__ short Vs[64][72];       // V^T[d][kv]
    __shared__ float Rs[4][36];        // per-wave row-sum redistribution

    int tid = threadIdx.x, wave = tid >> 6, lane = tid & 63;
    int lm = lane & 15, lq = lane >> 4;

    // Q fragments: B-operand of the swapped QK^T (lane lm = q column).
    bf16x8 qa[2][2];
#pragma unroll
    for (int qt = 0; qt < 2; qt++)
#pragma unroll
        for (int kf = 0; kf < 2; kf++)
            qa[qt][kf] = *(const bf16x8*)(xw + ((size_t)bh * 1024 + q0 + wave * 32 + qt * 16 + lm) * 64 + kf * 32 + lq * 8);

    f32x4 o[2][4];
#pragma unroll
    for (int qt = 0; qt < 2; qt++)
#pragma unroll
        for (int dt = 0; dt < 4; dt++) o[qt][dt] = (f32x4){0.f, 0.f, 0.f, 0.f};
    float rs[2] = {0.f, 0.f};

    // staging maps: thread stages 2x bf16x8 for K and 2 for V
    int ci0 = tid * 2, ci1 = tid * 2 + 1;
    int r0 = ci0 >> 3, s0 = (ci0 & 7) * 8;
    int r1 = ci1 >> 3, s1 = (ci1 & 7) * 8;
    const short* kg = xbf + ((size_t)(b * 1024)) * 1024 + h * 64;   // + (kv0+row)*1024 + seg
    const short* vg = vt + ((size_t)bh * 64) * 1024;                // + row*1024 + kv0 + seg
    // fp32 bias in [h][q][kv] layout; LOG2E applied at acc-init
    const float* bg = bias + ((size_t)h << 20) + (size_t)(q0 + wave * 32) * 1024;

    bf16x8 kr[2], vr[2];
    float4 br[4][2];
    // prefetch tile 0
    kr[0] = *(const bf16x8*)(kg + (size_t)r0 * 1024 + s0);
    kr[1] = *(const bf16x8*)(kg + (size_t)r1 * 1024 + s1);
    vr[0] = *(const bf16x8*)(vg + (size_t)r0 * 1024 + s0);
    vr[1] = *(const bf16x8*)(vg + (size_t)r1 * 1024 + s1);
#pragma unroll
    for (int kt = 0; kt < 4; kt++)
#pragma unroll
        for (int qt = 0; qt < 2; qt++)
            br[kt][qt] = *(const float4*)(bg + (size_t)(qt * 16 + lm) * 1024 + kt * 16 + lq * 4);
    *(bf16x8*)&Ks[r0][s0] = kr[0];
    *(bf16x8*)&Ks[r1][s1] = kr[1];
    *(bf16x8*)&Vs[r0][s0] = vr[0];
    *(bf16x8*)&Vs[r1][s1] = vr[1];

    for (int tile = 0; tile < 16; tile++) {
        int kv0 = tile * 64;
        __syncthreads();

        // acc init from prefetched fp32 bias regs (fold log2e here):
        // s[kt][qt] elem r -> (kv = kv0+kt*16+lq*4+r, q = q0+wave*32+qt*16+lm)
        f32x4 s[4][2];
#pragma unroll
        for (int kt = 0; kt < 4; kt++)
#pragma unroll
            for (int qt = 0; qt < 2; qt++) {
                float4 bv = br[kt][qt];
                s[kt][qt] = (f32x4){bv.x * LOG2E, bv.y * LOG2E, bv.z * LOG2E, bv.w * LOG2E};
            }

        // prefetch next tile (K, V, bias) into regs — overlaps compute
        if (tile < 15) {
            int kvn = kv0 + 64;
            kr[0] = *(const bf16x8*)(kg + (size_t)(kvn + r0) * 1024 + s0);
            kr[1] = *(const bf16x8*)(kg + (size_t)(kvn + r1) * 1024 + s1);
            vr[0] = *(const bf16x8*)(vg + (size_t)r0 * 1024 + kvn + s0);
            vr[1] = *(const bf16x8*)(vg + (size_t)r1 * 1024 + kvn + s1);
#pragma unroll
            for (int kt = 0; kt < 4; kt++)
#pragma unroll
                for (int qt = 0; qt < 2; qt++)
                    br[kt][qt] = *(const float4*)(bg + (size_t)(qt * 16 + lm) * 1024 + kvn + kt * 16 + lq * 4);
        }

        // S^T = K Q^T + bias  (A = K rows=kv, B = Q cols=q)
        __builtin_amdgcn_s_setprio(1);
#pragma unroll
        for (int kf = 0; kf < 2; kf++) {
            bf16x8 ka[4];
#pragma unroll
            for (int kt = 0; kt < 4; kt++)
                ka[kt] = *(const bf16x8*)&Ks[kt * 16 + lm][kf * 32 + lq * 8];
#pragma unroll
            for (int kt = 0; kt < 4; kt++)
#pragma unroll
                for (int qt = 0; qt < 2; qt++)
                    s[kt][qt] = __builtin_amdgcn_mfma_f32_16x16x32_bf16(ka[kt], qa[qt][kf], s[kt][qt], 0, 0, 0);
        }
        __builtin_amdgcn_s_setprio(0);

        // fixed-max softmax in place: p = exp2(s); accumulate partial row sums
#pragma unroll
        for (int kt = 0; kt < 4; kt++)
#pragma unroll
            for (int qt = 0; qt < 2; qt++)
#pragma unroll
                for (int r = 0; r < 4; r++) {
                    float pv = __builtin_amdgcn_exp2f(s[kt][qt][r]);
                    s[kt][qt][r] = pv;
                    rs[qt] += pv;
                }

        // O += P V.  P stays in registers; per-lane k-order for k-group lq is
        // {kf*32 + lq*4 + 0..3, kf*32 + 16 + lq*4 + 0..3}; V frag matches.
        __builtin_amdgcn_s_setprio(1);
#pragma unroll
        for (int kf = 0; kf < 2; kf++) {
            bf16x8 pa[2];
#pragma unroll
            for (int qt = 0; qt < 2; qt++) {
                U8 u;
                u.u[0] = cvtpk(s[kf * 2][qt][0], s[kf * 2][qt][1]);
                u.u[1] = cvtpk(s[kf * 2][qt][2], s[kf * 2][qt][3]);
                u.u[2] = cvtpk(s[kf * 2 + 1][qt][0], s[kf * 2 + 1][qt][1]);
                u.u[3] = cvtpk(s[kf * 2 + 1][qt][2], s[kf * 2 + 1][qt][3]);
                pa[qt] = u.v;
            }
#pragma unroll
            for (int dt = 0; dt < 4; dt++) {
                U8 uv;
                *(bf16x4*)&uv.u[0] = *(const bf16x4*)&Vs[dt * 16 + lm][kf * 32 + lq * 4];
                *(bf16x4*)&uv.u[2] = *(const bf16x4*)&Vs[dt * 16 + lm][kf * 32 + 16 + lq * 4];
#pragma unroll
                for (int qt = 0; qt < 2; qt++)
                    o[qt][dt] = __builtin_amdgcn_mfma_f32_16x16x32_bf16(pa[qt], uv.v, o[qt][dt], 0, 0, 0);
            }
        }
        __builtin_amdgcn_s_setprio(0);

        __syncthreads();
        if (tile < 15) {
            *(bf16x8*)&Ks[r0][s0] = kr[0];
            *(bf16x8*)&Ks[r1][s1] = kr[1];
            *(bf16x8*)&Vs[r0][s0] = vr[0];
            *(bf16x8*)&Vs[r1][s1] = vr[1];
        }
    }

    // row sums: butterfly across lq (lanes ^16, ^32), park in LDS, re-read at
    // the o-layout q index (lq*4+r).
#pragma unroll
    for (int qt = 0; qt < 2; qt++) {
        rs[qt] += __shfl_xor(rs[qt], 16);
        rs[qt] += __shfl_xor(rs[qt], 32);
    }
    if (lq == 0) { Rs[wave][lm] = rs[0]; Rs[wave][16 + lm] = rs[1]; }
    __syncthreads();

#pragma unroll
    for (int qt = 0; qt < 2; qt++) {
        float inv[4];
#pragma unroll
        for (int r = 0; r < 4; r++)
            inv[r] = 1.f / Rs[wave][qt * 16 + lq * 4 + r];
#pragma unroll
        for (int dt = 0; dt < 4; dt++) {
            int e = h * 64 + dt * 16 + lm;
#pragma unroll
            for (int r = 0; r < 4; r++) {
                int p = q0 + wave * 32 + qt * 16 + lq * 4 + r;
                obuf[((size_t)(b * 1024 + p)) * 1024 + e] = f2bf(o[qt][dt][r] * inv[r]);
            }
        }
    }
}

// ---------------------------------------------------------------------------
// Kernel 4: out = obuf @ out_w^T + out_b (fp32). m97-style staging,
// XCD-swizzled grid.
// ---------------------------------------------------------------------------
__global__ __launch_bounds__(256) void out_gemm(const short* __restrict__ obuf,
                                                const short* __restrict__ outwb,
                                                const float* __restrict__ outb,
                                                float* __restrict__ out) {
    int logical = (blockIdx.x & 7) * 128 + (blockIdx.x >> 3);
    int mblk = logical >> 3, nblk = logical & 7;
    int m0 = mblk * 128, n0 = nblk * 128;
    __shared__ short As[128 * 32];
    __shared__ short Bs[128 * 32];

    int tid = threadIdx.x;
    int wv = tid >> 6, ln = tid & 63;
    int c0 = wv * 2;
    int rrow = ln >> 2, rseg = (ln & 3) * 8;
    const short* gA = obuf + (size_t)(m0 + c0 * 16 + rrow) * 1024 + rseg;
    const short* gB = outwb + (size_t)(n0 + c0 * 16 + rrow) * 1024 + rseg;
    short* lA = As + c0 * 512;
    short* lB = Bs + c0 * 512;

    int lm = ln & 15, lq = ln >> 4;
    int wm = (wv >> 1) * 64, wn = (wv & 1) * 64;

    f32x4 acc[4][4];
#pragma unroll
    for (int i = 0; i < 4; i++)
#pragma unroll
        for (int j = 0; j < 4; j++) acc[i][j] = (f32x4){0.f, 0.f, 0.f, 0.f};

    for (int k0 = 0; k0 < 1024; k0 += 32) {
        __syncthreads();
        async16(gA + k0, lA);
        async16(gA + k0 + 16 * 1024, lA + 512);
        async16(gB + k0, lB);
        async16(gB + k0 + 16 * 1024, lB + 512);
        __syncthreads();
        bf16x8 af[4], bfr[4];
#pragma unroll
        for (int mt = 0; mt < 4; mt++) af[mt] = *(const bf16x8*)&As[(wm + mt * 16 + lm) * 32 + lq * 8];
#pragma unroll
        for (int nt = 0; nt < 4; nt++) bfr[nt] = *(const bf16x8*)&Bs[(wn + nt * 16 + lm) * 32 + lq * 8];
#pragma unroll
        for (int mt = 0; mt < 4; mt++)
#pragma unroll
            for (int nt = 0; nt < 4; nt++)
                acc[mt][nt] = __builtin_amdgcn_mfma_f32_16x16x32_bf16(af[mt], bfr[nt], acc[mt][nt], 0, 0, 0);
    }

#pragma unroll
    for (int nt = 0; nt < 4; nt++) {
        int e = n0 + wn + nt * 16 + lm;
        float bias = outb[e];
#pragma unroll
        for (int mt = 0; mt < 4; mt++) {
            int pg = m0 + wm + mt * 16 + lq * 4;
#pragma unroll
            for (int r = 0; r < 4; r++)
                out[(size_t)(pg + r) * 1024 + e] = acc[mt][nt][r] + bias;
        }
    }
}

extern "C" void kernel_launch(void* const* d_in, const int* in_sizes, int n_in,
                              void* d_out, int out_size, void* d_ws, size_t ws_size,
                              hipStream_t stream) {
    const float* x    = (const float*)d_in[0];  // [16,1024,1024]
    const float* watt = (const float*)d_in[1];  // [16,64,64]
    const float* bias = (const float*)d_in[2];  // [16,1024,1024]
    const float* wvw  = (const float*)d_in[3];  // [1024,1024]
    const float* wvb  = (const float*)d_in[4];  // [1024]
    const float* outw = (const float*)d_in[5];  // [1024,1024]
    const float* outb = (const float*)d_in[6];  // [1024]
    float* out = (float*)d_out;

    char* ws = (char*)d_ws;
    short* xw     = (short*)ws;                           // 32 MB  [B,H,P,DH] bf16 (Q, pre-scaled 0.125*log2e)
    short* vt     = (short*)(ws + ((size_t)32 << 20));    // 32 MB  [B,H,DH,P] bf16 (V^T)
    short* obuf   = (short*)(ws + ((size_t)64 << 20));    // 32 MB  [B,P,E]    bf16 (attn out)
    short* xbf    = (short*)(ws + ((size_t)96 << 20));    // 32 MB  [B,P,E]    bf16 (x)
    short* wvwb   = (short*)(ws + ((size_t)128 << 20));   // 2 MB
    short* outwb  = (short*)(ws + ((size_t)130 << 20));   // 2 MB

    xw_kernel<<<PB * PH * 4, 256, 0, stream>>>(x, watt, xw, xbf);
    wconv<<<1024, 256, 0, stream>>>(wvw, outw, wvwb, outwb);
    vx_gemm<<<(PB * PP / 128) * (PE / 128), 256, 0, stream>>>(xbf, wvwb, wvb, vt);
    flash_kernel<<<PB * PH * (PP / 128), 256, 0, stream>>>(xbf, xw, vt, bias, obuf);
    out_gemm<<<(PB * PP / 128) * (PE / 128), 256, 0, stream>>>(obuf, outwb, outb, out);
}

// Round 4
// 379.278 us; speedup vs baseline: 1.2792x; 1.1157x over previous
//
#include <hip/hip_runtime.h>

// Problem constants: B=16, P=1024, E=1024, H=16, DH=64
#define PB 16
#define PP 1024
#define PE 1024
#define PH 16
#define PDH 64

typedef __attribute__((ext_vector_type(8))) short bf16x8;
typedef __attribute__((ext_vector_type(4))) short bf16x4;
typedef __attribute__((ext_vector_type(4))) float f32x4;

#define LOG2E 1.44269504088896340736f

__device__ __forceinline__ short f2bf(float f) {
    union { float f; unsigned u; } a;
    a.f = f;
    unsigned u = a.u;
    u += 0x7fffu + ((u >> 16) & 1u);   // round-to-nearest-even
    return (short)(u >> 16);
}
__device__ __forceinline__ float bf2f(short s) {
    union { unsigned u; float f; } a;
    a.u = ((unsigned)(unsigned short)s) << 16;
    return a.f;
}
// pack two f32 -> one dword of 2 bf16 (src0 in low half)
__device__ __forceinline__ unsigned cvtpk(float lo, float hi) {
    unsigned r;
    asm("v_cvt_pk_bf16_f32 %0, %1, %2" : "=v"(r) : "v"(lo), "v"(hi));
    return r;
}
union U8 { unsigned u[4]; bf16x8 v; };
// async global->LDS, 16B per lane; LDS dest = wave-uniform base + lane*16
__device__ __forceinline__ void async16(const void* g, void* l) {
    __builtin_amdgcn_global_load_lds(
        (const __attribute__((address_space(1))) unsigned int*)g,
        (__attribute__((address_space(3))) unsigned int*)l, 16, 0, 0);
}

// ---------------------------------------------------------------------------
// Kernel 0a: bias_prep — bf16(bias*log2e) pre-blocked into flash's exact
// per-(tile,wave,lane) fragment order. Flash then reads 4 coalesced 16B
// loads per thread per tile (1KB contiguous per wave per load).
// Layout: biasP[h][tile][qblk][wave][j=kt(4)][lane(64)][8 shorts]
//   lane (lq,lm), short idx = qt*4 + r  ->
//   element (q = qblk*128 + wave*32 + qt*16 + lm, kv = tile*64 + kt*16 + lq*4 + r)
// ---------------------------------------------------------------------------
__global__ __launch_bounds__(256) void bias_prep(const float* __restrict__ bias,
                                                 short* __restrict__ biasP) {
    int bid = blockIdx.x;                       // grid 2048 = 16h * 8qblk * 16tile
    int h = bid >> 7, qblk = (bid >> 4) & 7, tile = bid & 15;
    int q0 = qblk * 128, kv0 = tile * 64;
    __shared__ short T[128][68];                // T[qrel][kvrel], 8B-aligned rows

    int t = threadIdx.x;
    {
        int qr = t >> 1, half = t & 1;
        const float* src = bias + ((size_t)h << 20) + (size_t)(q0 + qr) * 1024 + kv0 + half * 32;
#pragma unroll
        for (int i = 0; i < 32; i += 4) {
            float4 v = *(const float4*)(src + i);
            bf16x4 p = {f2bf(v.x * LOG2E), f2bf(v.y * LOG2E), f2bf(v.z * LOG2E), f2bf(v.w * LOG2E)};
            *(bf16x4*)&T[qr][half * 32 + i] = p;
        }
    }
    __syncthreads();

    int w = t >> 6, l = t & 63, lm = l & 15, lq = l >> 4;
    short* dst = biasP + (((size_t)(h * 16 + tile) * 8 + qblk) * 4 + w) * 2048 + l * 8;
#pragma unroll
    for (int j = 0; j < 4; j++) {
        bf16x4 a = *(const bf16x4*)&T[w * 32 + lm][j * 16 + lq * 4];        // qt=0
        bf16x4 b = *(const bf16x4*)&T[w * 32 + 16 + lm][j * 16 + lq * 4];   // qt=1
        bf16x8 o = {a[0], a[1], a[2], a[3], b[0], b[1], b[2], b[3]};
        *(bf16x8*)(dst + j * 512) = o;
    }
}

// ---------------------------------------------------------------------------
// Kernel 0b: weight fp32 -> bf16 (wv_w and out_w, both [n][k] row-major)
// ---------------------------------------------------------------------------
__global__ __launch_bounds__(256) void wconv(const float* __restrict__ wvw,
                                             const float* __restrict__ outw,
                                             short* __restrict__ wvwb,
                                             short* __restrict__ outwb) {
    int bid = blockIdx.x;
    const float* src = (bid < 512) ? wvw : outw;
    short* dst = (bid < 512) ? wvwb : outwb;
    int lb = (bid < 512) ? bid : bid - 512;
    size_t idx = ((size_t)lb * 256 + threadIdx.x) * 8;
    float4 a = *(const float4*)(src + idx);
    float4 b = *(const float4*)(src + idx + 4);
    bf16x8 t = {f2bf(a.x), f2bf(a.y), f2bf(a.z), f2bf(a.w),
                f2bf(b.x), f2bf(b.y), f2bf(b.z), f2bf(b.w)};
    *(bf16x8*)(dst + idx) = t;
}

// ---------------------------------------------------------------------------
// Kernel 1: xw = (x_h @ w_att_val[h]) * 0.125 * log2e (bf16)  AND  xbf = bf16(x)
// ---------------------------------------------------------------------------
__global__ __launch_bounds__(256) void xw_kernel(const float* __restrict__ x,
                                                 const float* __restrict__ watt,
                                                 short* __restrict__ xw,
                                                 short* __restrict__ xbf) {
    int bid = blockIdx.x;
    int q4 = bid & 3;
    int bh = bid >> 2;          // b*16 + h
    int h = bh & 15;
    __shared__ short Wt[64][88];   // W^T: Wt[e'][d]

    int tid = threadIdx.x;
    {
        const float* W = watt + (size_t)h * 4096;
        int idx = tid * 16;
        int d = idx >> 6, e0 = idx & 63;
#pragma unroll
        for (int i = 0; i < 16; i += 4) {
            float4 v = *(const float4*)(W + d * 64 + e0 + i);
            Wt[e0 + i + 0][d] = f2bf(v.x);
            Wt[e0 + i + 1][d] = f2bf(v.y);
            Wt[e0 + i + 2][d] = f2bf(v.z);
            Wt[e0 + i + 3][d] = f2bf(v.w);
        }
    }
    __syncthreads();

    int wave = tid >> 6, lane = tid & 63;
    int lm = lane & 15, lq = lane >> 4;

    bf16x8 bfr[4][2];
#pragma unroll
    for (int nt = 0; nt < 4; nt++)
#pragma unroll
        for (int kf = 0; kf < 2; kf++)
            bfr[nt][kf] = *(const bf16x8*)&Wt[nt * 16 + lm][kf * 32 + lq * 8];

    int b = bh >> 4;
    const float QSCALE = 0.125f * LOG2E;
    for (int pass = 0; pass < 4; pass++) {
        int p0 = q4 * 256 + pass * 64 + wave * 16;
        const float* xrow = x + ((size_t)(b * 1024 + p0 + lm)) * 1024 + h * 64;
        short* xorow = xbf + ((size_t)(b * 1024 + p0 + lm)) * 1024 + h * 64;
        bf16x8 af[2];
#pragma unroll
        for (int kf = 0; kf < 2; kf++) {
            float4 v0 = *(const float4*)(xrow + kf * 32 + lq * 8);
            float4 v1 = *(const float4*)(xrow + kf * 32 + lq * 8 + 4);
            bf16x8 t;
            t[0] = f2bf(v0.x); t[1] = f2bf(v0.y); t[2] = f2bf(v0.z); t[3] = f2bf(v0.w);
            t[4] = f2bf(v1.x); t[5] = f2bf(v1.y); t[6] = f2bf(v1.z); t[7] = f2bf(v1.w);
            af[kf] = t;
            *(bf16x8*)(xorow + kf * 32 + lq * 8) = t;   // bf16 copy of x
        }
#pragma unroll
        for (int nt = 0; nt < 4; nt++) {
            f32x4 acc = {0.f, 0.f, 0.f, 0.f};
            acc = __builtin_amdgcn_mfma_f32_16x16x32_bf16(af[0], bfr[nt][0], acc, 0, 0, 0);
            acc = __builtin_amdgcn_mfma_f32_16x16x32_bf16(af[1], bfr[nt][1], acc, 0, 0, 0);
            size_t base = ((size_t)bh * 1024 + p0 + lq * 4) * 64 + nt * 16 + lm;
#pragma unroll
            for (int r = 0; r < 4; r++)
                xw[base + (size_t)r * 64] = f2bf(acc[r] * QSCALE);
        }
    }
}

// ---------------------------------------------------------------------------
// Kernel 2: vt[b,h,d,p] = (x @ wv_w^T + wv_b) transposed (bf16).
// XCD-swizzled grid.
// ---------------------------------------------------------------------------
__global__ __launch_bounds__(256) void vx_gemm(const short* __restrict__ xbf,
                                               const short* __restrict__ wvwb,
                                               const float* __restrict__ wvb,
                                               short* __restrict__ vt) {
    int logical = (blockIdx.x & 7) * 128 + (blockIdx.x >> 3);   // grid 1024 = 8*128
    int mblk = logical >> 3, nblk = logical & 7;
    int m0 = mblk * 128, n0 = nblk * 128;
    __shared__ short As[128 * 32];
    __shared__ short Bs[128 * 32];

    int tid = threadIdx.x;
    int wv = tid >> 6, ln = tid & 63;
    int c0 = wv * 2;
    int rrow = ln >> 2, rseg = (ln & 3) * 8;
    const short* gA = xbf + (size_t)(m0 + c0 * 16 + rrow) * 1024 + rseg;
    const short* gB = wvwb + (size_t)(n0 + c0 * 16 + rrow) * 1024 + rseg;
    short* lA = As + c0 * 512;
    short* lB = Bs + c0 * 512;

    int lane = ln, lm = lane & 15, lq = lane >> 4;
    int wm = (wv >> 1) * 64, wn = (wv & 1) * 64;

    f32x4 acc[4][4];
#pragma unroll
    for (int i = 0; i < 4; i++)
#pragma unroll
        for (int j = 0; j < 4; j++) acc[i][j] = (f32x4){0.f, 0.f, 0.f, 0.f};

    for (int k0 = 0; k0 < 1024; k0 += 32) {
        __syncthreads();
        async16(gA + k0, lA);
        async16(gA + k0 + 16 * 1024, lA + 512);
        async16(gB + k0, lB);
        async16(gB + k0 + 16 * 1024, lB + 512);
        __syncthreads();
        bf16x8 af[4], bfr[4];
#pragma unroll
        for (int mt = 0; mt < 4; mt++) af[mt] = *(const bf16x8*)&As[(wm + mt * 16 + lm) * 32 + lq * 8];
#pragma unroll
        for (int nt = 0; nt < 4; nt++) bfr[nt] = *(const bf16x8*)&Bs[(wn + nt * 16 + lm) * 32 + lq * 8];
#pragma unroll
        for (int mt = 0; mt < 4; mt++)
#pragma unroll
            for (int nt = 0; nt < 4; nt++)
                acc[mt][nt] = __builtin_amdgcn_mfma_f32_16x16x32_bf16(af[mt], bfr[nt], acc[mt][nt], 0, 0, 0);
    }

#pragma unroll
    for (int nt = 0; nt < 4; nt++) {
        int e = n0 + wn + nt * 16 + lm;
        float bias = wvb[e];
        int hh = e >> 6, dd = e & 63;
#pragma unroll
        for (int mt = 0; mt < 4; mt++) {
            int pg = m0 + wm + mt * 16 + lq * 4;
            int bb = pg >> 10, pp = pg & 1023;
            bf16x4 pk;
#pragma unroll
            for (int r = 0; r < 4; r++) pk[r] = f2bf(acc[mt][nt][r] + bias);
            *(bf16x4*)(vt + ((size_t)((bb * 16 + hh) * 64 + dd)) * 1024 + pp) = pk;
        }
    }
}

// ---------------------------------------------------------------------------
// Kernel 3: flash attention v7 — register-staged K/V (round-1 structure),
// P in registers via swapped QK^T, XCD-swizzled grid, pre-blocked bf16 bias
// (4 coalesced 16B loads/thread/tile). No setprio (wrong regime: 4-wave
// lockstep block, m190).
// ---------------------------------------------------------------------------
__global__ __launch_bounds__(256, 3) void flash_kernel(const short* __restrict__ xbf,
                                                       const short* __restrict__ xw,
                                                       const short* __restrict__ vt,
                                                       const short* __restrict__ biasP,
                                                       short* __restrict__ obuf) {
    // XCD swizzle: grid 2048 = 8*256; consecutive logical ids share an XCD.
    int logical = (blockIdx.x & 7) * 256 + (blockIdx.x >> 3);
    int qblk = logical & 7, b = (logical >> 3) & 15, h = logical >> 7;
    int bh = b * 16 + h;
    int q0 = qblk * 128;

    __shared__ short Ks[64][72];       // K[kv][d]
    __shared__ short Vs[64][72];       // V^T[d][kv]
    __shared__ float Rs[4][36];        // per-wave row-sum redistribution

    int tid = threadIdx.x, wave = tid >> 6, lane = tid & 63;
    int lm = lane & 15, lq = lane >> 4;

    // Q fragments: B-operand of the swapped QK^T (lane lm = q column).
    bf16x8 qa[2][2];
#pragma unroll
    for (int qt = 0; qt < 2; qt++)
#pragma unroll
        for (int kf = 0; kf < 2; kf++)
            qa[qt][kf] = *(const bf16x8*)(xw + ((size_t)bh * 1024 + q0 + wave * 32 + qt * 16 + lm) * 64 + kf * 32 + lq * 8);

    f32x4 o[2][4];
#pragma unroll
    for (int qt = 0; qt < 2; qt++)
#pragma unroll
        for (int dt = 0; dt < 4; dt++) o[qt][dt] = (f32x4){0.f, 0.f, 0.f, 0.f};
    float rs[2] = {0.f, 0.f};

    // staging maps: thread stages 2x bf16x8 for K and 2 for V
    int ci0 = tid * 2, ci1 = tid * 2 + 1;
    int r0 = ci0 >> 3, s0 = (ci0 & 7) * 8;
    int r1 = ci1 >> 3, s1 = (ci1 & 7) * 8;
    const short* kg = xbf + ((size_t)(b * 1024)) * 1024 + h * 64;   // + (kv0+row)*1024 + seg
    const short* vg = vt + ((size_t)bh * 64) * 1024;                // + row*1024 + kv0 + seg
    // pre-blocked bf16 bias: per tile, 4 coalesced 16B loads per thread
    const short* bg = biasP + (((size_t)(h * 16) * 8 + qblk) * 4 + wave) * 2048 + lane * 8;
    const size_t BT_STRIDE = 65536;   // 8qblk*4wave*2048 shorts per tile

    bf16x8 kr[2], vr[2];
    bf16x8 br[4];
    // prefetch tile 0
    kr[0] = *(const bf16x8*)(kg + (size_t)r0 * 1024 + s0);
    kr[1] = *(const bf16x8*)(kg + (size_t)r1 * 1024 + s1);
    vr[0] = *(const bf16x8*)(vg + (size_t)r0 * 1024 + s0);
    vr[1] = *(const bf16x8*)(vg + (size_t)r1 * 1024 + s1);
#pragma unroll
    for (int kt = 0; kt < 4; kt++)
        br[kt] = *(const bf16x8*)(bg + kt * 512);
    *(bf16x8*)&Ks[r0][s0] = kr[0];
    *(bf16x8*)&Ks[r1][s1] = kr[1];
    *(bf16x8*)&Vs[r0][s0] = vr[0];
    *(bf16x8*)&Vs[r1][s1] = vr[1];

    for (int tile = 0; tile < 16; tile++) {
        int kv0 = tile * 64;
        __syncthreads();

        // acc init from prefetched bias regs:
        // s[kt][qt] elem r -> (kv = kv0+kt*16+lq*4+r, q = q0+wave*32+qt*16+lm)
        f32x4 s[4][2];
#pragma unroll
        for (int kt = 0; kt < 4; kt++)
#pragma unroll
            for (int qt = 0; qt < 2; qt++) {
                s[kt][qt] = (f32x4){bf2f(br[kt][qt * 4 + 0]), bf2f(br[kt][qt * 4 + 1]),
                                    bf2f(br[kt][qt * 4 + 2]), bf2f(br[kt][qt * 4 + 3])};
            }

        // prefetch next tile (K, V, bias) into regs — overlaps compute
        if (tile < 15) {
            int kvn = kv0 + 64;
            kr[0] = *(const bf16x8*)(kg + (size_t)(kvn + r0) * 1024 + s0);
            kr[1] = *(const bf16x8*)(kg + (size_t)(kvn + r1) * 1024 + s1);
            vr[0] = *(const bf16x8*)(vg + (size_t)r0 * 1024 + kvn + s0);
            vr[1] = *(const bf16x8*)(vg + (size_t)r1 * 1024 + kvn + s1);
            const short* bgn = bg + (size_t)(tile + 1) * BT_STRIDE;
#pragma unroll
            for (int kt = 0; kt < 4; kt++)
                br[kt] = *(const bf16x8*)(bgn + kt * 512);
        }

        // S^T = K Q^T + bias  (A = K rows=kv, B = Q cols=q)
#pragma unroll
        for (int kf = 0; kf < 2; kf++) {
            bf16x8 ka[4];
#pragma unroll
            for (int kt = 0; kt < 4; kt++)
                ka[kt] = *(const bf16x8*)&Ks[kt * 16 + lm][kf * 32 + lq * 8];
#pragma unroll
            for (int kt = 0; kt < 4; kt++)
#pragma unroll
                for (int qt = 0; qt < 2; qt++)
                    s[kt][qt] = __builtin_amdgcn_mfma_f32_16x16x32_bf16(ka[kt], qa[qt][kf], s[kt][qt], 0, 0, 0);
        }

        // fixed-max softmax in place: p = exp2(s); accumulate partial row sums
#pragma unroll
        for (int kt = 0; kt < 4; kt++)
#pragma unroll
            for (int qt = 0; qt < 2; qt++)
#pragma unroll
                for (int r = 0; r < 4; r++) {
                    float pv = __builtin_amdgcn_exp2f(s[kt][qt][r]);
                    s[kt][qt][r] = pv;
                    rs[qt] += pv;
                }

        // O += P V.  P stays in registers; per-lane k-order for k-group lq is
        // {kf*32 + lq*4 + 0..3, kf*32 + 16 + lq*4 + 0..3}; V frag matches.
#pragma unroll
        for (int kf = 0; kf < 2; kf++) {
            bf16x8 pa[2];
#pragma unroll
            for (int qt = 0; qt < 2; qt++) {
                U8 u;
                u.u[0] = cvtpk(s[kf * 2][qt][0], s[kf * 2][qt][1]);
                u.u[1] = cvtpk(s[kf * 2][qt][2], s[kf * 2][qt][3]);
                u.u[2] = cvtpk(s[kf * 2 + 1][qt][0], s[kf * 2 + 1][qt][1]);
                u.u[3] = cvtpk(s[kf * 2 + 1][qt][2], s[kf * 2 + 1][qt][3]);
                pa[qt] = u.v;
            }
#pragma unroll
            for (int dt = 0; dt < 4; dt++) {
                U8 uv;
                *(bf16x4*)&uv.u[0] = *(const bf16x4*)&Vs[dt * 16 + lm][kf * 32 + lq * 4];
                *(bf16x4*)&uv.u[2] = *(const bf16x4*)&Vs[dt * 16 + lm][kf * 32 + 16 + lq * 4];
#pragma unroll
                for (int qt = 0; qt < 2; qt++)
                    o[qt][dt] = __builtin_amdgcn_mfma_f32_16x16x32_bf16(pa[qt], uv.v, o[qt][dt], 0, 0, 0);
            }
        }

        __syncthreads();
        if (tile < 15) {
            *(bf16x8*)&Ks[r0][s0] = kr[0];
            *(bf16x8*)&Ks[r1][s1] = kr[1];
            *(bf16x8*)&Vs[r0][s0] = vr[0];
            *(bf16x8*)&Vs[r1][s1] = vr[1];
        }
    }

    // row sums: butterfly across lq (lanes ^16, ^32), park in LDS, re-read at
    // the o-layout q index (lq*4+r).
#pragma unroll
    for (int qt = 0; qt < 2; qt++) {
        rs[qt] += __shfl_xor(rs[qt], 16);
        rs[qt] += __shfl_xor(rs[qt], 32);
    }
    if (lq == 0) { Rs[wave][lm] = rs[0]; Rs[wave][16 + lm] = rs[1]; }
    __syncthreads();

#pragma unroll
    for (int qt = 0; qt < 2; qt++) {
        float inv[4];
#pragma unroll
        for (int r = 0; r < 4; r++)
            inv[r] = 1.f / Rs[wave][qt * 16 + lq * 4 + r];
#pragma unroll
        for (int dt = 0; dt < 4; dt++) {
            int e = h * 64 + dt * 16 + lm;
#pragma unroll
            for (int r = 0; r < 4; r++) {
                int p = q0 + wave * 32 + qt * 16 + lq * 4 + r;
                obuf[((size_t)(b * 1024 + p)) * 1024 + e] = f2bf(o[qt][dt][r] * inv[r]);
            }
        }
    }
}

// ---------------------------------------------------------------------------
// Kernel 4: out = obuf @ out_w^T + out_b (fp32). m97-style staging,
// XCD-swizzled grid.
// ---------------------------------------------------------------------------
__global__ __launch_bounds__(256) void out_gemm(const short* __restrict__ obuf,
                                                const short* __restrict__ outwb,
                                                const float* __restrict__ outb,
                                                float* __restrict__ out) {
    int logical = (blockIdx.x & 7) * 128 + (blockIdx.x >> 3);
    int mblk = logical >> 3, nblk = logical & 7;
    int m0 = mblk * 128, n0 = nblk * 128;
    __shared__ short As[128 * 32];
    __shared__ short Bs[128 * 32];

    int tid = threadIdx.x;
    int wv = tid >> 6, ln = tid & 63;
    int c0 = wv * 2;
    int rrow = ln >> 2, rseg = (ln & 3) * 8;
    const short* gA = obuf + (size_t)(m0 + c0 * 16 + rrow) * 1024 + rseg;
    const short* gB = outwb + (size_t)(n0 + c0 * 16 + rrow) * 1024 + rseg;
    short* lA = As + c0 * 512;
    short* lB = Bs + c0 * 512;

    int lm = ln & 15, lq = ln >> 4;
    int wm = (wv >> 1) * 64, wn = (wv & 1) * 64;

    f32x4 acc[4][4];
#pragma unroll
    for (int i = 0; i < 4; i++)
#pragma unroll
        for (int j = 0; j < 4; j++) acc[i][j] = (f32x4){0.f, 0.f, 0.f, 0.f};

    for (int k0 = 0; k0 < 1024; k0 += 32) {
        __syncthreads();
        async16(gA + k0, lA);
        async16(gA + k0 + 16 * 1024, lA + 512);
        async16(gB + k0, lB);
        async16(gB + k0 + 16 * 1024, lB + 512);
        __syncthreads();
        bf16x8 af[4], bfr[4];
#pragma unroll
        for (int mt = 0; mt < 4; mt++) af[mt] = *(const bf16x8*)&As[(wm + mt * 16 + lm) * 32 + lq * 8];
#pragma unroll
        for (int nt = 0; nt < 4; nt++) bfr[nt] = *(const bf16x8*)&Bs[(wn + nt * 16 + lm) * 32 + lq * 8];
#pragma unroll
        for (int mt = 0; mt < 4; mt++)
#pragma unroll
            for (int nt = 0; nt < 4; nt++)
                acc[mt][nt] = __builtin_amdgcn_mfma_f32_16x16x32_bf16(af[mt], bfr[nt], acc[mt][nt], 0, 0, 0);
    }

#pragma unroll
    for (int nt = 0; nt < 4; nt++) {
        int e = n0 + wn + nt * 16 + lm;
        float bias = outb[e];
#pragma unroll
        for (int mt = 0; mt < 4; mt++) {
            int pg = m0 + wm + mt * 16 + lq * 4;
#pragma unroll
            for (int r = 0; r < 4; r++)
                out[(size_t)(pg + r) * 1024 + e] = acc[mt][nt][r] + bias;
        }
    }
}

extern "C" void kernel_launch(void* const* d_in, const int* in_sizes, int n_in,
                              void* d_out, int out_size, void* d_ws, size_t ws_size,
                              hipStream_t stream) {
    const float* x    = (const float*)d_in[0];  // [16,1024,1024]
    const float* watt = (const float*)d_in[1];  // [16,64,64]
    const float* bias = (const float*)d_in[2];  // [16,1024,1024]
    const float* wvw  = (const float*)d_in[3];  // [1024,1024]
    const float* wvb  = (const float*)d_in[4];  // [1024]
    const float* outw = (const float*)d_in[5];  // [1024,1024]
    const float* outb = (const float*)d_in[6];  // [1024]
    float* out = (float*)d_out;

    char* ws = (char*)d_ws;
    short* xw     = (short*)ws;                           // 32 MB  [B,H,P,DH] bf16 (Q, pre-scaled 0.125*log2e)
    short* vt     = (short*)(ws + ((size_t)32 << 20));    // 32 MB  [B,H,DH,P] bf16 (V^T)
    short* obuf   = (short*)(ws + ((size_t)64 << 20));    // 32 MB  [B,P,E]    bf16 (attn out)
    short* xbf    = (short*)(ws + ((size_t)96 << 20));    // 32 MB  [B,P,E]    bf16 (x)
    short* biasP  = (short*)(ws + ((size_t)128 << 20));   // 32 MB  blocked bf16 bias*log2e
    short* wvwb   = (short*)(ws + ((size_t)160 << 20));   // 2 MB
    short* outwb  = (short*)(ws + ((size_t)162 << 20));   // 2 MB

    xw_kernel<<<PB * PH * 4, 256, 0, stream>>>(x, watt, xw, xbf);
    bias_prep<<<2048, 256, 0, stream>>>(bias, biasP);
    wconv<<<1024, 256, 0, stream>>>(wvw, outw, wvwb, outwb);
    vx_gemm<<<(PB * PP / 128) * (PE / 128), 256, 0, stream>>>(xbf, wvwb, wvb, vt);
    flash_kernel<<<PB * PH * (PP / 128), 256, 0, stream>>>(xbf, xw, vt, biasP, obuf);
    out_gemm<<<(PB * PP / 128) * (PE / 128), 256, 0, stream>>>(obuf, outwb, outb, out);
}